// Round 2
// baseline (898.288 us; speedup 1.0000x reference)
//
#include <hip/hip_runtime.h>
#include <hip/hip_bf16.h>
#include <math.h>

// Problem constants (from setup_inputs): B=16, T=16, O=10, L=160, d=768,
// heads=12, head_dim=64, H=W=14, TEMPORAL_RES=8 -> Tr=2, out=(16,1568,768) fp32.

#define BATCH 16
#define TT    16
#define OO    10
#define LL    160            // T*O
#define BL    2560           // BATCH*LL
#define DD    768
#define NH    12
#define DH    64
#define GH    14
#define GW    14
#define TGRP  8              // T / Tr
#define ATT_CHUNK 80

// ---------------------------------------------------------------------------
// 1) box MLP: x = relu(relu(box @ w1) @ w2) + cat[t,o]   (8 rows per block)
//    NOTE: box_categories is (T=16, O=10, d) broadcast over B — index (t,o)!
// ---------------------------------------------------------------------------
__global__ __launch_bounds__(256)
void box_mlp(const float* __restrict__ box, const float* __restrict__ cat,
             const float* __restrict__ w1, const float* __restrict__ w2,
             float* __restrict__ x)
{
    __shared__ float hbuf[8][384];
    const int r0 = blockIdx.x * 8;
    const int tid = threadIdx.x;

#pragma unroll
    for (int k = 0; k < 12; ++k) {
        int idx = tid + k * 256;          // 0..3071
        int i = idx / 384, j = idx - i * 384;
        const float* bx = box + (size_t)(r0 + i) * 4;
        float v = bx[0] * w1[j] + bx[1] * w1[384 + j] +
                  bx[2] * w1[768 + j] + bx[3] * w1[1152 + j];
        hbuf[i][j] = fmaxf(v, 0.f);
    }
    __syncthreads();

    float acc[8][3];
#pragma unroll
    for (int i = 0; i < 8; ++i) { acc[i][0] = 0.f; acc[i][1] = 0.f; acc[i][2] = 0.f; }

    for (int j = 0; j < 384; ++j) {
        const float wa = w2[(size_t)j * DD + tid];
        const float wb = w2[(size_t)j * DD + tid + 256];
        const float wc = w2[(size_t)j * DD + tid + 512];
#pragma unroll
        for (int i = 0; i < 8; ++i) {
            float hv = hbuf[i][j];
            acc[i][0] += hv * wa; acc[i][1] += hv * wb; acc[i][2] += hv * wc;
        }
    }

#pragma unroll
    for (int i = 0; i < 8; ++i) {
        int r = r0 + i;
        int to = r % LL;                  // t*OO + o  (cat broadcast over B)
        const float* cp = cat + (size_t)to * DD;
        float* xp = x + (size_t)r * DD;
        xp[tid]       = fmaxf(acc[i][0], 0.f) + cp[tid];
        xp[tid + 256] = fmaxf(acc[i][1], 0.f) + cp[tid + 256];
        xp[tid + 512] = fmaxf(acc[i][2], 0.f) + cp[tid + 512];
    }
}

// ---------------------------------------------------------------------------
// 2) LayerNorm: out = (x - mu) * rsqrt(var + 1e-5) * g + b   (block per row)
// ---------------------------------------------------------------------------
__global__ __launch_bounds__(256)
void ln_kernel(const float* __restrict__ in, const float* __restrict__ g,
               const float* __restrict__ bvec, float* __restrict__ out)
{
    const int r = blockIdx.x;
    const int tid = threadIdx.x;
    const float* row = in + (size_t)r * DD;
    float v0 = row[tid], v1 = row[tid + 256], v2 = row[tid + 512];
    float s  = v0 + v1 + v2;
    float s2 = v0 * v0 + v1 * v1 + v2 * v2;
#pragma unroll
    for (int off = 32; off > 0; off >>= 1) {
        s  += __shfl_down(s, off);
        s2 += __shfl_down(s2, off);
    }
    __shared__ float red[8];
    int wave = tid >> 6, lane = tid & 63;
    if (lane == 0) { red[wave] = s; red[wave + 4] = s2; }
    __syncthreads();
    s  = red[0] + red[1] + red[2] + red[3];
    s2 = red[4] + red[5] + red[6] + red[7];
    float mu  = s * (1.f / DD);
    float var = s2 * (1.f / DD) - mu * mu;
    float inv = rsqrtf(var + 1e-5f);
    float* op = out + (size_t)r * DD;
    op[tid]       = (v0 - mu) * inv * g[tid]       + bvec[tid];
    op[tid + 256] = (v1 - mu) * inv * g[tid + 256] + bvec[tid + 256];
    op[tid + 512] = (v2 - mu) * inv * g[tid + 512] + bvec[tid + 512];
}

// ---------------------------------------------------------------------------
// 3) fp32 GEMM, 64x64 tile, 256 threads, 4x4 per thread.
//    MODE 0: C = A@B
//    MODE 1: C += A@B + bias       (residual in-place)
//    MODE 2: C = gelu(A@B + bias)  (exact gelu)
// ---------------------------------------------------------------------------
template <int MODE>
__global__ __launch_bounds__(256)
void gemm64(const float* __restrict__ A, int lda,
            const float* __restrict__ Bm, int ldb,
            const float* __restrict__ bias,
            float* __restrict__ C, int ldc, int K)
{
    __shared__ float Ast[16][68];   // [kk][row], padded
    __shared__ float Bs[16][64];    // [kk][col]

    const int tid = threadIdx.x;
    const int tx = tid & 15, ty = tid >> 4;
    const int row0 = blockIdx.y * 64;
    const int col0 = blockIdx.x * 64;

    float acc[4][4];
#pragma unroll
    for (int i = 0; i < 4; ++i)
#pragma unroll
        for (int j = 0; j < 4; ++j) acc[i][j] = 0.f;

    const int ar = tid >> 2;           // 0..63
    const int ak = (tid & 3) * 4;      // 0,4,8,12
    const int bk = tid >> 4;           // 0..15
    const int bc = (tid & 15) * 4;     // 0..60

    const float* Aptr = A + (size_t)(row0 + ar) * lda + ak;
    const float* Bptr = Bm + (size_t)bk * ldb + col0 + bc;

    for (int kt = 0; kt < K; kt += 16) {
        float4 av = *(const float4*)Aptr;  Aptr += 16;
        float4 bv = *(const float4*)Bptr;  Bptr += (size_t)16 * ldb;
        Ast[ak + 0][ar] = av.x; Ast[ak + 1][ar] = av.y;
        Ast[ak + 2][ar] = av.z; Ast[ak + 3][ar] = av.w;
        *(float4*)&Bs[bk][bc] = bv;
        __syncthreads();
#pragma unroll
        for (int kk = 0; kk < 16; ++kk) {
            float4 a4 = *(const float4*)&Ast[kk][ty * 4];
            float4 b4 = *(const float4*)&Bs[kk][tx * 4];
            float av_[4] = {a4.x, a4.y, a4.z, a4.w};
            float bv_[4] = {b4.x, b4.y, b4.z, b4.w};
#pragma unroll
            for (int i = 0; i < 4; ++i)
#pragma unroll
                for (int j = 0; j < 4; ++j)
                    acc[i][j] += av_[i] * bv_[j];
        }
        __syncthreads();
    }

#pragma unroll
    for (int i = 0; i < 4; ++i) {
        int r = row0 + ty * 4 + i;
        float* crow = C + (size_t)r * ldc + col0 + tx * 4;
        float4 res;
        float v[4];
#pragma unroll
        for (int j = 0; j < 4; ++j) v[j] = acc[i][j];
        if (MODE == 0) {
            res.x = v[0]; res.y = v[1]; res.z = v[2]; res.w = v[3];
        } else if (MODE == 1) {
            float4 old = *(const float4*)crow;
            res.x = old.x + v[0] + bias[col0 + tx * 4 + 0];
            res.y = old.y + v[1] + bias[col0 + tx * 4 + 1];
            res.z = old.z + v[2] + bias[col0 + tx * 4 + 2];
            res.w = old.w + v[3] + bias[col0 + tx * 4 + 3];
        } else {
            float t[4];
#pragma unroll
            for (int j = 0; j < 4; ++j) {
                float u = v[j] + bias[col0 + tx * 4 + j];
                t[j] = 0.5f * u * (1.f + erff(u * 0.70710678118654752f));
            }
            res.x = t[0]; res.y = t[1]; res.z = t[2]; res.w = t[3];
        }
        *(float4*)crow = res;
    }
}

// ---------------------------------------------------------------------------
// 4) attention, one block per (b, head); thread per q-row; two-pass softmax;
//    K/V staged in LDS in 80-row chunks; output overwrites q slot of qkv.
// ---------------------------------------------------------------------------
__global__ __launch_bounds__(192)
void attention(float* __restrict__ qkv)
{
    __shared__ float Ks[ATT_CHUNK * DH];
    __shared__ float Vs[ATT_CHUNK * DH];
    const int b  = blockIdx.x / NH;
    const int hh = blockIdx.x % NH;
    float* base = qkv + (size_t)b * LL * (3 * DD) + hh * DH;
    const int tid = threadIdx.x;
    const bool active = tid < LL;

    float q[DH];
    if (active) {
        const float* qrow = base + (size_t)tid * (3 * DD);
#pragma unroll
        for (int d4 = 0; d4 < 16; ++d4) {
            float4 t = *(const float4*)(qrow + d4 * 4);
            q[d4 * 4 + 0] = t.x; q[d4 * 4 + 1] = t.y;
            q[d4 * 4 + 2] = t.z; q[d4 * 4 + 3] = t.w;
        }
    }

    float m = -1e30f;
    for (int c = 0; c < 2; ++c) {
        for (int idx = tid; idx < ATT_CHUNK * 16; idx += 192) {
            int l = idx >> 4, d4 = idx & 15;
            *(float4*)&Ks[l * DH + d4 * 4] =
                *(const float4*)(base + (size_t)(c * ATT_CHUNK + l) * (3 * DD) + DD + d4 * 4);
        }
        __syncthreads();
        if (active) {
            for (int j = 0; j < ATT_CHUNK; ++j) {
                float s = 0.f;
#pragma unroll
                for (int d4 = 0; d4 < 16; ++d4) {
                    float4 kv = *(const float4*)&Ks[j * DH + d4 * 4];
                    s += q[d4 * 4 + 0] * kv.x + q[d4 * 4 + 1] * kv.y +
                         q[d4 * 4 + 2] * kv.z + q[d4 * 4 + 3] * kv.w;
                }
                m = fmaxf(m, s * 0.125f);
            }
        }
        __syncthreads();
    }

    float suml = 0.f;
    float o[DH];
#pragma unroll
    for (int d = 0; d < DH; ++d) o[d] = 0.f;

    for (int c = 0; c < 2; ++c) {
        for (int idx = tid; idx < ATT_CHUNK * 16; idx += 192) {
            int l = idx >> 4, d4 = idx & 15;
            const float* krow = base + (size_t)(c * ATT_CHUNK + l) * (3 * DD);
            *(float4*)&Ks[l * DH + d4 * 4] = *(const float4*)(krow + DD + d4 * 4);
            *(float4*)&Vs[l * DH + d4 * 4] = *(const float4*)(krow + 2 * DD + d4 * 4);
        }
        __syncthreads();
        if (active) {
            for (int j = 0; j < ATT_CHUNK; ++j) {
                float s = 0.f;
#pragma unroll
                for (int d4 = 0; d4 < 16; ++d4) {
                    float4 kv = *(const float4*)&Ks[j * DH + d4 * 4];
                    s += q[d4 * 4 + 0] * kv.x + q[d4 * 4 + 1] * kv.y +
                         q[d4 * 4 + 2] * kv.z + q[d4 * 4 + 3] * kv.w;
                }
                float e = __expf(s * 0.125f - m);
                suml += e;
#pragma unroll
                for (int d4 = 0; d4 < 16; ++d4) {
                    float4 vv = *(const float4*)&Vs[j * DH + d4 * 4];
                    o[d4 * 4 + 0] += e * vv.x; o[d4 * 4 + 1] += e * vv.y;
                    o[d4 * 4 + 2] += e * vv.z; o[d4 * 4 + 3] += e * vv.w;
                }
            }
        }
        __syncthreads();
    }

    if (active) {
        float inv = 1.f / suml;
        float* orow = base + (size_t)tid * (3 * DD);   // overwrite q slot
#pragma unroll
        for (int d4 = 0; d4 < 16; ++d4) {
            float4 t;
            t.x = o[d4 * 4 + 0] * inv; t.y = o[d4 * 4 + 1] * inv;
            t.z = o[d4 * 4 + 2] * inv; t.w = o[d4 * 4 + 3] * inv;
            *(float4*)(orow + d4 * 4) = t;
        }
    }
}

// ---------------------------------------------------------------------------
// 5) mask + grid aggregation + temporal mean:
//    out[b, g*196+h*14+w, :] = 0.5 * sum_{t in {2g,2g+1}} sum_o mask * feats
// ---------------------------------------------------------------------------
__global__ __launch_bounds__(256)
void mask_grid(const float* __restrict__ box, const float* __restrict__ feats,
               float* __restrict__ out)
{
    const int hw = blockIdx.x;     // 0..195
    const int g  = blockIdx.y;     // 0..7
    const int b  = blockIdx.z;     // 0..15
    const int hh = hw / GW, w = hw % GW;
    const float cy = (hh + 0.5f) / (float)GH;
    const float cx = (w  + 0.5f) / (float)GW;
    const int tid = threadIdx.x;

    __shared__ float flg[20];
    if (tid < 20) {
        int t = g * 2 + tid / OO, o = tid % OO;
        const float* bx = box + (size_t)((b * TT + t) * OO + o) * 4;
        float x1 = fminf(bx[0], bx[2]), x2 = fmaxf(bx[0], bx[2]);
        float y1 = fminf(bx[1], bx[3]), y2 = fmaxf(bx[1], bx[3]);
        flg[tid] = (cy >= y1 && cy <= y2 && cx >= x1 && cx <= x2) ? 1.f : 0.f;
    }
    __syncthreads();

    float a0 = 0.f, a1 = 0.f, a2 = 0.f;
#pragma unroll
    for (int p = 0; p < 20; ++p) {
        if (flg[p] != 0.f) {                 // wave-uniform branch
            int r = (b * TT + g * 2 + p / OO) * OO + (p % OO);
            const float* f = feats + (size_t)r * DD;
            a0 += f[tid]; a1 += f[tid + 256]; a2 += f[tid + 512];
        }
    }
    float* op = out + ((size_t)b * (TGRP * GH * GW) + g * (GH * GW) + hw) * DD;
    op[tid]       = a0 * 0.5f;
    op[tid + 256] = a1 * 0.5f;
    op[tid + 512] = a2 * 0.5f;
}

// ---------------------------------------------------------------------------
extern "C" void kernel_launch(void* const* d_in, const int* in_sizes, int n_in,
                              void* d_out, int out_size, void* d_ws, size_t ws_size,
                              hipStream_t stream)
{
    const float* box  = (const float*)d_in[0];
    const float* cat  = (const float*)d_in[1];
    const float* w1   = (const float*)d_in[2];
    const float* w2   = (const float*)d_in[3];
    const float* ln1g = (const float*)d_in[4];
    const float* ln1b = (const float*)d_in[5];
    const float* wqkv = (const float*)d_in[6];
    const float* wo   = (const float*)d_in[7];
    const float* bo   = (const float*)d_in[8];
    const float* ln2g = (const float*)d_in[9];
    const float* ln2b = (const float*)d_in[10];
    const float* wfc1 = (const float*)d_in[11];
    const float* bfc1 = (const float*)d_in[12];
    const float* wfc2 = (const float*)d_in[13];
    const float* bfc2 = (const float*)d_in[14];
    float* out = (float*)d_out;

    float* ws  = (float*)d_ws;
    float* x   = ws;                    // 2560*768
    float* hn  = ws + 1966080;          // 2560*768
    float* qkv = ws + 3932160;          // 2560*2304
    float* fc1 = ws + 3932160;          // 2560*3072 (overlays qkv; qkv dead by then)

    box_mlp<<<BL / 8, 256, 0, stream>>>(box, cat, w1, w2, x);
    ln_kernel<<<BL, 256, 0, stream>>>(x, ln1g, ln1b, hn);
    gemm64<0><<<dim3(2304 / 64, BL / 64), 256, 0, stream>>>(hn, DD, wqkv, 3 * DD, nullptr, qkv, 3 * DD, DD);
    attention<<<BATCH * NH, 192, 0, stream>>>(qkv);
    gemm64<1><<<dim3(DD / 64, BL / 64), 256, 0, stream>>>(qkv, 3 * DD, wo, DD, bo, x, DD, DD);
    ln_kernel<<<BL, 256, 0, stream>>>(x, ln2g, ln2b, hn);
    gemm64<2><<<dim3(3072 / 64, BL / 64), 256, 0, stream>>>(hn, DD, wfc1, 4 * DD, bfc1, fc1, 4 * DD, DD);
    gemm64<1><<<dim3(DD / 64, BL / 64), 256, 0, stream>>>(fc1, 4 * DD, wfc2, DD, bfc2, x, DD, 4 * DD);
    mask_grid<<<dim3(GH * GW, TGRP, BATCH), 256, 0, stream>>>(box, x, out);
}

// Round 3
// 550.729 us; speedup vs baseline: 1.6311x; 1.6311x over previous
//
#include <hip/hip_runtime.h>
#include <hip/hip_bf16.h>
#include <math.h>

// B=16, T=16, O=10, L=160, d=768, heads=12, dh=64, H=W=14, Tr=2.
// Out: (16, 8*196, 768) fp32.

#define BATCH 16
#define TT    16
#define OO    10
#define LL    160
#define BL    2560
#define DD    768
#define NH    12
#define DH    64
#define GH    14
#define GW    14
#define TGRP  8
#define ATT_CHUNK 80

typedef unsigned short ushort_t;
typedef __attribute__((ext_vector_type(8))) __bf16 bf16x8;
typedef __attribute__((ext_vector_type(4))) float f32x4;

__device__ __forceinline__ ushort_t f2bf(float f) {
    unsigned int u = __float_as_uint(f);
    u += 0x7fffu + ((u >> 16) & 1u);         // RNE
    return (ushort_t)(u >> 16);
}
__device__ __forceinline__ float bf2f_lo(unsigned int u) { return __uint_as_float(u << 16); }
__device__ __forceinline__ float bf2f_hi(unsigned int u) { return __uint_as_float(u & 0xffff0000u); }

// ---------------------------------------------------------------------------
// 0) weight convert+transpose: W[K][N] fp32 -> Wt[N][K] bf16
// ---------------------------------------------------------------------------
__global__ __launch_bounds__(256)
void transpose_w(const float* __restrict__ W, ushort_t* __restrict__ Wt, int K, int N)
{
    __shared__ float s[32][33];
    const int n0 = blockIdx.x * 32, k0 = blockIdx.y * 32;
    const int tx = threadIdx.x & 31, ty = threadIdx.x >> 5;   // ty 0..7
#pragma unroll
    for (int r = 0; r < 4; ++r)
        s[ty + r * 8][tx] = W[(size_t)(k0 + ty + r * 8) * N + n0 + tx];
    __syncthreads();
#pragma unroll
    for (int r = 0; r < 4; ++r)
        Wt[(size_t)(n0 + ty + r * 8) * K + k0 + tx] = f2bf(s[tx][ty + r * 8]);
}

// ---------------------------------------------------------------------------
// 1) box MLP: x = relu(relu(box @ w1) @ w2) + cat[t,o]
// ---------------------------------------------------------------------------
__global__ __launch_bounds__(256)
void box_mlp(const float* __restrict__ box, const float* __restrict__ cat,
             const float* __restrict__ w1, const float* __restrict__ w2,
             float* __restrict__ x)
{
    __shared__ float hbuf[8][384];
    const int r0 = blockIdx.x * 8;
    const int tid = threadIdx.x;

#pragma unroll
    for (int k = 0; k < 12; ++k) {
        int idx = tid + k * 256;
        int i = idx / 384, j = idx - i * 384;
        const float* bx = box + (size_t)(r0 + i) * 4;
        float v = bx[0] * w1[j] + bx[1] * w1[384 + j] +
                  bx[2] * w1[768 + j] + bx[3] * w1[1152 + j];
        hbuf[i][j] = fmaxf(v, 0.f);
    }
    __syncthreads();

    float acc[8][3];
#pragma unroll
    for (int i = 0; i < 8; ++i) { acc[i][0] = 0.f; acc[i][1] = 0.f; acc[i][2] = 0.f; }

    for (int j = 0; j < 384; ++j) {
        const float wa = w2[(size_t)j * DD + tid];
        const float wb = w2[(size_t)j * DD + tid + 256];
        const float wc = w2[(size_t)j * DD + tid + 512];
#pragma unroll
        for (int i = 0; i < 8; ++i) {
            float hv = hbuf[i][j];
            acc[i][0] += hv * wa; acc[i][1] += hv * wb; acc[i][2] += hv * wc;
        }
    }

#pragma unroll
    for (int i = 0; i < 8; ++i) {
        int r = r0 + i;
        int to = r % LL;                     // cat is (T,O,d), broadcast over B
        const float* cp = cat + (size_t)to * DD;
        float* xp = x + (size_t)r * DD;
        xp[tid]       = fmaxf(acc[i][0], 0.f) + cp[tid];
        xp[tid + 256] = fmaxf(acc[i][1], 0.f) + cp[tid + 256];
        xp[tid + 512] = fmaxf(acc[i][2], 0.f) + cp[tid + 512];
    }
}

// ---------------------------------------------------------------------------
// 2) LayerNorm -> bf16 output
// ---------------------------------------------------------------------------
__global__ __launch_bounds__(256)
void ln_kernel(const float* __restrict__ in, const float* __restrict__ g,
               const float* __restrict__ bvec, ushort_t* __restrict__ out)
{
    const int r = blockIdx.x;
    const int tid = threadIdx.x;
    const float* row = in + (size_t)r * DD;
    float v0 = row[tid], v1 = row[tid + 256], v2 = row[tid + 512];
    float s  = v0 + v1 + v2;
    float s2 = v0 * v0 + v1 * v1 + v2 * v2;
#pragma unroll
    for (int off = 32; off > 0; off >>= 1) {
        s  += __shfl_down(s, off);
        s2 += __shfl_down(s2, off);
    }
    __shared__ float red[8];
    int wave = tid >> 6, lane = tid & 63;
    if (lane == 0) { red[wave] = s; red[wave + 4] = s2; }
    __syncthreads();
    s  = red[0] + red[1] + red[2] + red[3];
    s2 = red[4] + red[5] + red[6] + red[7];
    float mu  = s * (1.f / DD);
    float var = s2 * (1.f / DD) - mu * mu;
    float inv = rsqrtf(var + 1e-5f);
    ushort_t* op = out + (size_t)r * DD;
    op[tid]       = f2bf((v0 - mu) * inv * g[tid]       + bvec[tid]);
    op[tid + 256] = f2bf((v1 - mu) * inv * g[tid + 256] + bvec[tid + 256]);
    op[tid + 512] = f2bf((v2 - mu) * inv * g[tid + 512] + bvec[tid + 512]);
}

// ---------------------------------------------------------------------------
// 3) bf16 MFMA GEMM, 128x128 tile, BK=32, 256 thr (4 waves, 64x64 each).
//    A[M][K] bf16 row-major; Bt[N][K] bf16 row-major (weights pre-transposed).
//    MODE 1: Cf += acc + bias (fp32)   MODE 2: Cb = bf16(gelu(acc+bias))
//    MODE 3: Cb = bf16(acc)
// ---------------------------------------------------------------------------
template <int MODE>
__global__ __launch_bounds__(256)
void gemm_mfma(const ushort_t* __restrict__ A, int lda,
               const ushort_t* __restrict__ Bt, int ldb,
               const float* __restrict__ bias,
               float* __restrict__ Cf, ushort_t* __restrict__ Cb,
               int ldc, int K)
{
    __shared__ ushort_t As[128 * 32];
    __shared__ ushort_t Bs[128 * 32];
    const int tid  = threadIdx.x;
    const int wave = tid >> 6, lane = tid & 63;
    const int wr = wave >> 1, wc = wave & 1;
    const int row0 = blockIdx.y * 128, col0 = blockIdx.x * 128;

    f32x4 acc[4][4];
#pragma unroll
    for (int i = 0; i < 4; ++i)
#pragma unroll
        for (int j = 0; j < 4; ++j) {
            acc[i][j][0] = 0.f; acc[i][j][1] = 0.f;
            acc[i][j][2] = 0.f; acc[i][j][3] = 0.f;
        }

    const int srow = lane >> 2;          // 0..15
    const int scol = (lane & 3) * 8;     // ushort offset (16B chunks)
    const int q8 = (lane >> 4) * 8;
    const int mr = lane & 15;

    for (int kt = 0; kt < K; kt += 32) {
#pragma unroll
        for (int t = 0; t < 2; ++t) {
            const int inst = wave * 2 + t;                       // 0..7
            const ushort_t* ga = A + (size_t)(row0 + inst * 16 + srow) * lda + kt + scol;
            __builtin_amdgcn_global_load_lds(
                (const __attribute__((address_space(1))) void*)ga,
                (__attribute__((address_space(3))) void*)&As[inst * 512], 16, 0, 0);
            const ushort_t* gb = Bt + (size_t)(col0 + inst * 16 + srow) * ldb + kt + scol;
            __builtin_amdgcn_global_load_lds(
                (const __attribute__((address_space(1))) void*)gb,
                (__attribute__((address_space(3))) void*)&Bs[inst * 512], 16, 0, 0);
        }
        __syncthreads();   // drains vmcnt (global_load_lds) + orders LDS

        bf16x8 af[4], bfr[4];
#pragma unroll
        for (int i = 0; i < 4; ++i)
            af[i] = *reinterpret_cast<const bf16x8*>(&As[(wr * 64 + i * 16 + mr) * 32 + q8]);
#pragma unroll
        for (int j = 0; j < 4; ++j)
            bfr[j] = *reinterpret_cast<const bf16x8*>(&Bs[(wc * 64 + j * 16 + mr) * 32 + q8]);
#pragma unroll
        for (int i = 0; i < 4; ++i)
#pragma unroll
            for (int j = 0; j < 4; ++j)
                acc[i][j] = __builtin_amdgcn_mfma_f32_16x16x32_bf16(af[i], bfr[j], acc[i][j], 0, 0, 0);
        __syncthreads();
    }

    // epilogue: C/D layout col=lane&15, row=(lane>>4)*4+reg
    const int q4 = (lane >> 4) * 4;
#pragma unroll
    for (int i = 0; i < 4; ++i)
#pragma unroll
        for (int j = 0; j < 4; ++j) {
            const int gcol = col0 + wc * 64 + j * 16 + mr;
            const float bj = (MODE == 1 || MODE == 2) ? bias[gcol] : 0.f;
#pragma unroll
            for (int r = 0; r < 4; ++r) {
                const int grow = row0 + wr * 64 + i * 16 + q4 + r;
                const size_t idx = (size_t)grow * ldc + gcol;
                const float v = acc[i][j][r];
                if (MODE == 1) {
                    Cf[idx] += v + bj;
                } else if (MODE == 2) {
                    const float u = v + bj;
                    Cb[idx] = f2bf(0.5f * u * (1.f + erff(u * 0.70710678118654752f)));
                } else {
                    Cb[idx] = f2bf(v);
                }
            }
        }
}

// ---------------------------------------------------------------------------
// 4) attention: bf16 qkv in, bf16 o out; fp32 math; block per (b,head)
// ---------------------------------------------------------------------------
__global__ __launch_bounds__(192)
void attention(const ushort_t* __restrict__ qkv, ushort_t* __restrict__ ao)
{
    __shared__ float Ks[ATT_CHUNK * DH];
    __shared__ float Vs[ATT_CHUNK * DH];
    const int b  = blockIdx.x / NH;
    const int hh = blockIdx.x % NH;
    const ushort_t* base = qkv + (size_t)b * LL * (3 * DD) + hh * DH;
    const int tid = threadIdx.x;
    const bool active = tid < LL;

    float q[DH];
    if (active) {
        const ushort_t* qrow = base + (size_t)tid * (3 * DD);
#pragma unroll
        for (int c8 = 0; c8 < 8; ++c8) {
            uint4 raw = *(const uint4*)(qrow + c8 * 8);
            q[c8 * 8 + 0] = bf2f_lo(raw.x); q[c8 * 8 + 1] = bf2f_hi(raw.x);
            q[c8 * 8 + 2] = bf2f_lo(raw.y); q[c8 * 8 + 3] = bf2f_hi(raw.y);
            q[c8 * 8 + 4] = bf2f_lo(raw.z); q[c8 * 8 + 5] = bf2f_hi(raw.z);
            q[c8 * 8 + 6] = bf2f_lo(raw.w); q[c8 * 8 + 7] = bf2f_hi(raw.w);
        }
    }

    float m = -1e30f;
    for (int c = 0; c < 2; ++c) {
        for (int idx = tid; idx < ATT_CHUNK * 8; idx += 192) {
            int l = idx >> 3, d8 = (idx & 7) * 8;
            uint4 raw = *(const uint4*)(base + (size_t)(c * ATT_CHUNK + l) * (3 * DD) + DD + d8);
            float* ks = &Ks[l * DH + d8];
            ks[0] = bf2f_lo(raw.x); ks[1] = bf2f_hi(raw.x);
            ks[2] = bf2f_lo(raw.y); ks[3] = bf2f_hi(raw.y);
            ks[4] = bf2f_lo(raw.z); ks[5] = bf2f_hi(raw.z);
            ks[6] = bf2f_lo(raw.w); ks[7] = bf2f_hi(raw.w);
        }
        __syncthreads();
        if (active) {
            for (int j = 0; j < ATT_CHUNK; ++j) {
                float s = 0.f;
#pragma unroll
                for (int d4 = 0; d4 < 16; ++d4) {
                    float4 kv = *(const float4*)&Ks[j * DH + d4 * 4];
                    s += q[d4 * 4 + 0] * kv.x + q[d4 * 4 + 1] * kv.y +
                         q[d4 * 4 + 2] * kv.z + q[d4 * 4 + 3] * kv.w;
                }
                m = fmaxf(m, s * 0.125f);
            }
        }
        __syncthreads();
    }

    float suml = 0.f;
    float o[DH];
#pragma unroll
    for (int d = 0; d < DH; ++d) o[d] = 0.f;

    for (int c = 0; c < 2; ++c) {
        for (int idx = tid; idx < ATT_CHUNK * 8; idx += 192) {
            int l = idx >> 3, d8 = (idx & 7) * 8;
            const ushort_t* krow = base + (size_t)(c * ATT_CHUNK + l) * (3 * DD);
            uint4 rk = *(const uint4*)(krow + DD + d8);
            uint4 rv = *(const uint4*)(krow + 2 * DD + d8);
            float* ks = &Ks[l * DH + d8];
            float* vs = &Vs[l * DH + d8];
            ks[0] = bf2f_lo(rk.x); ks[1] = bf2f_hi(rk.x);
            ks[2] = bf2f_lo(rk.y); ks[3] = bf2f_hi(rk.y);
            ks[4] = bf2f_lo(rk.z); ks[5] = bf2f_hi(rk.z);
            ks[6] = bf2f_lo(rk.w); ks[7] = bf2f_hi(rk.w);
            vs[0] = bf2f_lo(rv.x); vs[1] = bf2f_hi(rv.x);
            vs[2] = bf2f_lo(rv.y); vs[3] = bf2f_hi(rv.y);
            vs[4] = bf2f_lo(rv.z); vs[5] = bf2f_hi(rv.z);
            vs[6] = bf2f_lo(rv.w); vs[7] = bf2f_hi(rv.w);
        }
        __syncthreads();
        if (active) {
            for (int j = 0; j < ATT_CHUNK; ++j) {
                float s = 0.f;
#pragma unroll
                for (int d4 = 0; d4 < 16; ++d4) {
                    float4 kv = *(const float4*)&Ks[j * DH + d4 * 4];
                    s += q[d4 * 4 + 0] * kv.x + q[d4 * 4 + 1] * kv.y +
                         q[d4 * 4 + 2] * kv.z + q[d4 * 4 + 3] * kv.w;
                }
                float e = __expf(s * 0.125f - m);
                suml += e;
#pragma unroll
                for (int d4 = 0; d4 < 16; ++d4) {
                    float4 vv = *(const float4*)&Vs[j * DH + d4 * 4];
                    o[d4 * 4 + 0] += e * vv.x; o[d4 * 4 + 1] += e * vv.y;
                    o[d4 * 4 + 2] += e * vv.z; o[d4 * 4 + 3] += e * vv.w;
                }
            }
        }
        __syncthreads();
    }

    if (active) {
        float inv = 1.f / suml;
        ushort_t* orow = ao + (size_t)(b * LL + tid) * DD + hh * DH;
#pragma unroll
        for (int c8 = 0; c8 < 8; ++c8) {
            uint4 u;
            u.x = (unsigned)f2bf(o[c8 * 8 + 0] * inv) | ((unsigned)f2bf(o[c8 * 8 + 1] * inv) << 16);
            u.y = (unsigned)f2bf(o[c8 * 8 + 2] * inv) | ((unsigned)f2bf(o[c8 * 8 + 3] * inv) << 16);
            u.z = (unsigned)f2bf(o[c8 * 8 + 4] * inv) | ((unsigned)f2bf(o[c8 * 8 + 5] * inv) << 16);
            u.w = (unsigned)f2bf(o[c8 * 8 + 6] * inv) | ((unsigned)f2bf(o[c8 * 8 + 7] * inv) << 16);
            *(uint4*)(orow + c8 * 8) = u;
        }
    }
}

// ---------------------------------------------------------------------------
// 5) mask + grid aggregation + temporal mean
// ---------------------------------------------------------------------------
__global__ __launch_bounds__(256)
void mask_grid(const float* __restrict__ box, const float* __restrict__ feats,
               float* __restrict__ out)
{
    const int hw = blockIdx.x;
    const int g  = blockIdx.y;
    const int b  = blockIdx.z;
    const int hh = hw / GW, w = hw % GW;
    const float cy = (hh + 0.5f) / (float)GH;
    const float cx = (w  + 0.5f) / (float)GW;
    const int tid = threadIdx.x;

    __shared__ float flg[20];
    if (tid < 20) {
        int t = g * 2 + tid / OO, o = tid % OO;
        const float* bx = box + (size_t)((b * TT + t) * OO + o) * 4;
        float x1 = fminf(bx[0], bx[2]), x2 = fmaxf(bx[0], bx[2]);
        float y1 = fminf(bx[1], bx[3]), y2 = fmaxf(bx[1], bx[3]);
        flg[tid] = (cy >= y1 && cy <= y2 && cx >= x1 && cx <= x2) ? 1.f : 0.f;
    }
    __syncthreads();

    float a0 = 0.f, a1 = 0.f, a2 = 0.f;
#pragma unroll
    for (int p = 0; p < 20; ++p) {
        if (flg[p] != 0.f) {
            int r = (b * TT + g * 2 + p / OO) * OO + (p % OO);
            const float* f = feats + (size_t)r * DD;
            a0 += f[tid]; a1 += f[tid + 256]; a2 += f[tid + 512];
        }
    }
    float* op = out + ((size_t)b * (TGRP * GH * GW) + g * (GH * GW) + hw) * DD;
    op[tid]       = a0 * 0.5f;
    op[tid + 256] = a1 * 0.5f;
    op[tid + 512] = a2 * 0.5f;
}

// ---------------------------------------------------------------------------
extern "C" void kernel_launch(void* const* d_in, const int* in_sizes, int n_in,
                              void* d_out, int out_size, void* d_ws, size_t ws_size,
                              hipStream_t stream)
{
    const float* box  = (const float*)d_in[0];
    const float* cat  = (const float*)d_in[1];
    const float* w1   = (const float*)d_in[2];
    const float* w2   = (const float*)d_in[3];
    const float* ln1g = (const float*)d_in[4];
    const float* ln1b = (const float*)d_in[5];
    const float* wqkv = (const float*)d_in[6];
    const float* wo   = (const float*)d_in[7];
    const float* bo   = (const float*)d_in[8];
    const float* ln2g = (const float*)d_in[9];
    const float* ln2b = (const float*)d_in[10];
    const float* wfc1 = (const float*)d_in[11];
    const float* bfc1 = (const float*)d_in[12];
    const float* wfc2 = (const float*)d_in[13];
    const float* bfc2 = (const float*)d_in[14];
    float* out = (float*)d_out;

    // workspace layout (byte offsets, all 16B aligned)
    char* wsb = (char*)d_ws;
    float*    x     = (float*)   (wsb + 0);           //  7,864,320 B (2560x768 f32)
    ushort_t* qkvb  = (ushort_t*)(wsb + 7864320);     // 11,796,480 B (2560x2304 bf16)
    ushort_t* fc1b  = qkvb;                           // 15,728,640 B overlay (qkv dead)
    ushort_t* hnb   = (ushort_t*)(wsb + 23592960);    //  3,932,160 B
    ushort_t* aob   = (ushort_t*)(wsb + 27525120);    //  3,932,160 B
    ushort_t* wqkvT = (ushort_t*)(wsb + 31457280);    //  3,538,944 B (2304x768)
    ushort_t* woT   = (ushort_t*)(wsb + 34996224);    //  1,179,648 B (768x768)
    ushort_t* wfc1T = (ushort_t*)(wsb + 36175872);    //  4,718,592 B (3072x768)
    ushort_t* wfc2T = (ushort_t*)(wsb + 40894464);    //  4,718,592 B (768x3072)
    // total 45,613,056 B

    transpose_w<<<dim3(2304 / 32, 768 / 32), 256, 0, stream>>>(wqkv, wqkvT, 768, 2304);
    transpose_w<<<dim3(768 / 32, 768 / 32), 256, 0, stream>>>(wo, woT, 768, 768);
    transpose_w<<<dim3(3072 / 32, 768 / 32), 256, 0, stream>>>(wfc1, wfc1T, 768, 3072);
    transpose_w<<<dim3(768 / 32, 3072 / 32), 256, 0, stream>>>(wfc2, wfc2T, 3072, 768);

    box_mlp<<<BL / 8, 256, 0, stream>>>(box, cat, w1, w2, x);
    ln_kernel<<<BL, 256, 0, stream>>>(x, ln1g, ln1b, hnb);
    gemm_mfma<3><<<dim3(18, 20), 256, 0, stream>>>(hnb, DD, wqkvT, DD, nullptr,
                                                   nullptr, qkvb, 3 * DD, DD);
    attention<<<BATCH * NH, 192, 0, stream>>>(qkvb, aob);
    gemm_mfma<1><<<dim3(6, 20), 256, 0, stream>>>(aob, DD, woT, DD, bo,
                                                  x, nullptr, DD, DD);
    ln_kernel<<<BL, 256, 0, stream>>>(x, ln2g, ln2b, hnb);
    gemm_mfma<2><<<dim3(24, 20), 256, 0, stream>>>(hnb, DD, wfc1T, DD, bfc1,
                                                   nullptr, fc1b, 4 * DD, DD);
    gemm_mfma<1><<<dim3(6, 20), 256, 0, stream>>>(fc1b, 4 * DD, wfc2T, 4 * DD, bfc2,
                                                  x, nullptr, DD, 4 * DD);
    mask_grid<<<dim3(GH * GW, TGRP, BATCH), 256, 0, stream>>>(box, x, out);
}

// Round 4
// 405.525 us; speedup vs baseline: 2.2151x; 1.3581x over previous
//
#include <hip/hip_runtime.h>
#include <hip/hip_bf16.h>
#include <math.h>

// B=16, T=16, O=10, L=160, d=768, heads=12, dh=64, H=W=14, Tr=2.
// Out: (16, 8*196, 768) fp32.

#define BATCH 16
#define TT    16
#define OO    10
#define LL    160
#define BL    2560
#define DD    768
#define NH    12
#define DH    64
#define GH    14
#define GW    14
#define TGRP  8

typedef unsigned short ushort_t;
typedef __attribute__((ext_vector_type(8))) __bf16 bf16x8;
typedef __attribute__((ext_vector_type(4))) float f32x4;

__device__ __forceinline__ ushort_t f2bf(float f) {
    unsigned int u = __float_as_uint(f);
    u += 0x7fffu + ((u >> 16) & 1u);         // RNE
    return (ushort_t)(u >> 16);
}

// ---------------------------------------------------------------------------
// 0) weight convert+transpose: W[K][N] fp32 -> Wt[N][K] bf16
// ---------------------------------------------------------------------------
__global__ __launch_bounds__(256)
void transpose_w(const float* __restrict__ W, ushort_t* __restrict__ Wt, int K, int N)
{
    __shared__ float s[32][33];
    const int n0 = blockIdx.x * 32, k0 = blockIdx.y * 32;
    const int tx = threadIdx.x & 31, ty = threadIdx.x >> 5;   // ty 0..7
#pragma unroll
    for (int r = 0; r < 4; ++r)
        s[ty + r * 8][tx] = W[(size_t)(k0 + ty + r * 8) * N + n0 + tx];
    __syncthreads();
#pragma unroll
    for (int r = 0; r < 4; ++r)
        Wt[(size_t)(n0 + ty + r * 8) * K + k0 + tx] = f2bf(s[tx][ty + r * 8]);
}

// ---------------------------------------------------------------------------
// 1) box MLP: x = relu(relu(box @ w1) @ w2) + cat[t,o]
// ---------------------------------------------------------------------------
__global__ __launch_bounds__(256)
void box_mlp(const float* __restrict__ box, const float* __restrict__ cat,
             const float* __restrict__ w1, const float* __restrict__ w2,
             float* __restrict__ x)
{
    __shared__ float hbuf[8][384];
    const int r0 = blockIdx.x * 8;
    const int tid = threadIdx.x;

#pragma unroll
    for (int k = 0; k < 12; ++k) {
        int idx = tid + k * 256;
        int i = idx / 384, j = idx - i * 384;
        const float* bx = box + (size_t)(r0 + i) * 4;
        float v = bx[0] * w1[j] + bx[1] * w1[384 + j] +
                  bx[2] * w1[768 + j] + bx[3] * w1[1152 + j];
        hbuf[i][j] = fmaxf(v, 0.f);
    }
    __syncthreads();

    float acc[8][3];
#pragma unroll
    for (int i = 0; i < 8; ++i) { acc[i][0] = 0.f; acc[i][1] = 0.f; acc[i][2] = 0.f; }

    for (int j = 0; j < 384; ++j) {
        const float wa = w2[(size_t)j * DD + tid];
        const float wb = w2[(size_t)j * DD + tid + 256];
        const float wc = w2[(size_t)j * DD + tid + 512];
#pragma unroll
        for (int i = 0; i < 8; ++i) {
            float hv = hbuf[i][j];
            acc[i][0] += hv * wa; acc[i][1] += hv * wb; acc[i][2] += hv * wc;
        }
    }

#pragma unroll
    for (int i = 0; i < 8; ++i) {
        int r = r0 + i;
        int to = r % LL;                     // cat is (T,O,d), broadcast over B
        const float* cp = cat + (size_t)to * DD;
        float* xp = x + (size_t)r * DD;
        xp[tid]       = fmaxf(acc[i][0], 0.f) + cp[tid];
        xp[tid + 256] = fmaxf(acc[i][1], 0.f) + cp[tid + 256];
        xp[tid + 512] = fmaxf(acc[i][2], 0.f) + cp[tid + 512];
    }
}

// ---------------------------------------------------------------------------
// 2) LayerNorm -> bf16 output
// ---------------------------------------------------------------------------
__global__ __launch_bounds__(256)
void ln_kernel(const float* __restrict__ in, const float* __restrict__ g,
               const float* __restrict__ bvec, ushort_t* __restrict__ out)
{
    const int r = blockIdx.x;
    const int tid = threadIdx.x;
    const float* row = in + (size_t)r * DD;
    float v0 = row[tid], v1 = row[tid + 256], v2 = row[tid + 512];
    float s  = v0 + v1 + v2;
    float s2 = v0 * v0 + v1 * v1 + v2 * v2;
#pragma unroll
    for (int off = 32; off > 0; off >>= 1) {
        s  += __shfl_down(s, off);
        s2 += __shfl_down(s2, off);
    }
    __shared__ float red[8];
    int wave = tid >> 6, lane = tid & 63;
    if (lane == 0) { red[wave] = s; red[wave + 4] = s2; }
    __syncthreads();
    s  = red[0] + red[1] + red[2] + red[3];
    s2 = red[4] + red[5] + red[6] + red[7];
    float mu  = s * (1.f / DD);
    float var = s2 * (1.f / DD) - mu * mu;
    float inv = rsqrtf(var + 1e-5f);
    ushort_t* op = out + (size_t)r * DD;
    op[tid]       = f2bf((v0 - mu) * inv * g[tid]       + bvec[tid]);
    op[tid + 256] = f2bf((v1 - mu) * inv * g[tid + 256] + bvec[tid + 256]);
    op[tid + 512] = f2bf((v2 - mu) * inv * g[tid + 512] + bvec[tid + 512]);
}

// ---------------------------------------------------------------------------
// 3) bf16 MFMA GEMM, 128x128 tile, BK=32, 256 thr (4 waves, 64x64 each).
//    A[M][K] bf16 row-major; Bt[N][K] bf16 row-major (weights pre-transposed).
//    MODE 1: Cf += acc + bias (fp32)   MODE 2: Cb = bf16(gelu(acc+bias))
//    MODE 3: Cb = bf16(acc)
// ---------------------------------------------------------------------------
template <int MODE>
__global__ __launch_bounds__(256)
void gemm_mfma(const ushort_t* __restrict__ A, int lda,
               const ushort_t* __restrict__ Bt, int ldb,
               const float* __restrict__ bias,
               float* __restrict__ Cf, ushort_t* __restrict__ Cb,
               int ldc, int K)
{
    __shared__ ushort_t As[128 * 32];
    __shared__ ushort_t Bs[128 * 32];
    const int tid  = threadIdx.x;
    const int wave = tid >> 6, lane = tid & 63;
    const int wr = wave >> 1, wc = wave & 1;
    const int row0 = blockIdx.y * 128, col0 = blockIdx.x * 128;

    f32x4 acc[4][4];
#pragma unroll
    for (int i = 0; i < 4; ++i)
#pragma unroll
        for (int j = 0; j < 4; ++j) {
            acc[i][j][0] = 0.f; acc[i][j][1] = 0.f;
            acc[i][j][2] = 0.f; acc[i][j][3] = 0.f;
        }

    const int srow = lane >> 2;          // 0..15
    const int scol = (lane & 3) * 8;     // ushort offset (16B chunks)
    const int q8 = (lane >> 4) * 8;
    const int mr = lane & 15;

    for (int kt = 0; kt < K; kt += 32) {
#pragma unroll
        for (int t = 0; t < 2; ++t) {
            const int inst = wave * 2 + t;                       // 0..7
            const ushort_t* ga = A + (size_t)(row0 + inst * 16 + srow) * lda + kt + scol;
            __builtin_amdgcn_global_load_lds(
                (const __attribute__((address_space(1))) void*)ga,
                (__attribute__((address_space(3))) void*)&As[inst * 512], 16, 0, 0);
            const ushort_t* gb = Bt + (size_t)(col0 + inst * 16 + srow) * ldb + kt + scol;
            __builtin_amdgcn_global_load_lds(
                (const __attribute__((address_space(1))) void*)gb,
                (__attribute__((address_space(3))) void*)&Bs[inst * 512], 16, 0, 0);
        }
        __syncthreads();   // drains vmcnt (global_load_lds) + orders LDS

        bf16x8 af[4], bfr[4];
#pragma unroll
        for (int i = 0; i < 4; ++i)
            af[i] = *reinterpret_cast<const bf16x8*>(&As[(wr * 64 + i * 16 + mr) * 32 + q8]);
#pragma unroll
        for (int j = 0; j < 4; ++j)
            bfr[j] = *reinterpret_cast<const bf16x8*>(&Bs[(wc * 64 + j * 16 + mr) * 32 + q8]);
#pragma unroll
        for (int i = 0; i < 4; ++i)
#pragma unroll
            for (int j = 0; j < 4; ++j)
                acc[i][j] = __builtin_amdgcn_mfma_f32_16x16x32_bf16(af[i], bfr[j], acc[i][j], 0, 0, 0);
        __syncthreads();
    }

    // epilogue: C/D layout col=lane&15, row=(lane>>4)*4+reg
    const int q4 = (lane >> 4) * 4;
#pragma unroll
    for (int i = 0; i < 4; ++i)
#pragma unroll
        for (int j = 0; j < 4; ++j) {
            const int gcol = col0 + wc * 64 + j * 16 + mr;
            const float bj = (MODE == 1 || MODE == 2) ? bias[gcol] : 0.f;
#pragma unroll
            for (int r = 0; r < 4; ++r) {
                const int grow = row0 + wr * 64 + i * 16 + q4 + r;
                const size_t idx = (size_t)grow * ldc + gcol;
                const float v = acc[i][j][r];
                if (MODE == 1) {
                    Cf[idx] += v + bj;
                } else if (MODE == 2) {
                    const float u = v + bj;
                    Cb[idx] = f2bf(0.5f * u * (1.f + erff(u * 0.70710678118654752f)));
                } else {
                    Cb[idx] = f2bf(v);
                }
            }
        }
}

// ---------------------------------------------------------------------------
// 4) MFMA attention: block per (b,head), 5 waves; wave w owns q rows
//    [32w,32w+32) as two 16-row MFMA tiles. K staged [160][72] LDS, V staged
//    transposed Vt[64][168]. S via mfma(Q,K) (frag layouts HW-verified by
//    gemm_mfma); softmax in-register (quad shfl_xor); P -> LDS (bf16, /l);
//    O^T = mfma(Vt, P) so output regs are 4 consecutive d's -> 8B stores.
// ---------------------------------------------------------------------------
#define KS_STRIDE 72
#define VT_STRIDE 168
__global__ __launch_bounds__(320)
void attention_mfma(const ushort_t* __restrict__ qkv, ushort_t* __restrict__ ao)
{
    __shared__ ushort_t Ks[160 * KS_STRIDE];
    __shared__ ushort_t Vt[64 * VT_STRIDE];
    __shared__ ushort_t Pb[5][32 * VT_STRIDE];

    const int b  = blockIdx.x / NH;
    const int hh = blockIdx.x % NH;
    const ushort_t* base = qkv + (size_t)b * LL * (3 * DD) + hh * DH;
    const int tid  = threadIdx.x;
    const int wave = tid >> 6, lane = tid & 63;
    const int l16 = lane & 15, quad = lane >> 4;

    // ---- stage K rows (8 x uint4 per row) and V transposed ----
#pragma unroll
    for (int it = 0; it < 4; ++it) {
        int idx = tid + it * 320;                 // 0..1279
        int l = idx >> 3, c8 = (idx & 7) * 8;
        uint4 kv = *(const uint4*)(base + (size_t)l * (3 * DD) + DD + c8);
        *(uint4*)&Ks[l * KS_STRIDE + c8] = kv;
        uint4 vv = *(const uint4*)(base + (size_t)l * (3 * DD) + 2 * DD + c8);
        ushort_t e[8];
        *(uint4*)e = vv;
#pragma unroll
        for (int i = 0; i < 8; ++i)
            Vt[(c8 + i) * VT_STRIDE + l] = e[i];
    }

    // ---- Q fragments straight from global (2 tiles x 2 k-steps) ----
    const int q0 = wave * 32;
    bf16x8 qf[2][2];
#pragma unroll
    for (int t = 0; t < 2; ++t)
#pragma unroll
        for (int k = 0; k < 2; ++k)
            qf[t][k] = *reinterpret_cast<const bf16x8*>(
                base + (size_t)(q0 + t * 16 + l16) * (3 * DD) + k * 32 + quad * 8);

    __syncthreads();

    // ---- S = QK^T (shared K frags across both q-tiles) ----
    f32x4 S0[10], S1[10];
#pragma unroll
    for (int nt = 0; nt < 10; ++nt) {
        f32x4 z = {0.f, 0.f, 0.f, 0.f};
        const ushort_t* kb = &Ks[(nt * 16 + l16) * KS_STRIDE + quad * 8];
        bf16x8 kf0 = *reinterpret_cast<const bf16x8*>(kb);
        bf16x8 kf1 = *reinterpret_cast<const bf16x8*>(kb + 32);
        f32x4 a0 = __builtin_amdgcn_mfma_f32_16x16x32_bf16(qf[0][0], kf0, z, 0, 0, 0);
        S0[nt]   = __builtin_amdgcn_mfma_f32_16x16x32_bf16(qf[0][1], kf1, a0, 0, 0, 0);
        f32x4 a1 = __builtin_amdgcn_mfma_f32_16x16x32_bf16(qf[1][0], kf0, z, 0, 0, 0);
        S1[nt]   = __builtin_amdgcn_mfma_f32_16x16x32_bf16(qf[1][1], kf1, a1, 0, 0, 0);
    }

    // ---- softmax per tile; write P (already / l) to wave-private LDS ----
#pragma unroll
    for (int t = 0; t < 2; ++t) {
        f32x4* S = t ? S1 : S0;
        float mrow[4] = {-1e30f, -1e30f, -1e30f, -1e30f};
#pragma unroll
        for (int nt = 0; nt < 10; ++nt)
#pragma unroll
            for (int r = 0; r < 4; ++r) {
                S[nt][r] *= 0.125f;
                mrow[r] = fmaxf(mrow[r], S[nt][r]);
            }
#pragma unroll
        for (int r = 0; r < 4; ++r) {
            mrow[r] = fmaxf(mrow[r], __shfl_xor(mrow[r], 1));
            mrow[r] = fmaxf(mrow[r], __shfl_xor(mrow[r], 2));
            mrow[r] = fmaxf(mrow[r], __shfl_xor(mrow[r], 4));
            mrow[r] = fmaxf(mrow[r], __shfl_xor(mrow[r], 8));
        }
        float lsum[4] = {0.f, 0.f, 0.f, 0.f};
#pragma unroll
        for (int nt = 0; nt < 10; ++nt)
#pragma unroll
            for (int r = 0; r < 4; ++r) {
                float e = __expf(S[nt][r] - mrow[r]);
                S[nt][r] = e;
                lsum[r] += e;
            }
#pragma unroll
        for (int r = 0; r < 4; ++r) {
            lsum[r] += __shfl_xor(lsum[r], 1);
            lsum[r] += __shfl_xor(lsum[r], 2);
            lsum[r] += __shfl_xor(lsum[r], 4);
            lsum[r] += __shfl_xor(lsum[r], 8);
            lsum[r] = 1.f / lsum[r];
        }
#pragma unroll
        for (int nt = 0; nt < 10; ++nt)
#pragma unroll
            for (int r = 0; r < 4; ++r)
                Pb[wave][(t * 16 + quad * 4 + r) * VT_STRIDE + nt * 16 + l16] =
                    f2bf(S[nt][r] * lsum[r]);
    }
    asm volatile("s_waitcnt lgkmcnt(0)" ::: "memory");   // wave-local P write->read

    // ---- O^T = Vt . P^T : D[m=d][n=q]; store 4 consecutive d per lane ----
#pragma unroll
    for (int dt = 0; dt < 4; ++dt) {
        f32x4 o0 = {0.f, 0.f, 0.f, 0.f}, o1 = {0.f, 0.f, 0.f, 0.f};
#pragma unroll
        for (int ks = 0; ks < 5; ++ks) {
            bf16x8 vf = *reinterpret_cast<const bf16x8*>(
                &Vt[(dt * 16 + l16) * VT_STRIDE + ks * 32 + quad * 8]);
            bf16x8 p0 = *reinterpret_cast<const bf16x8*>(
                &Pb[wave][(l16) * VT_STRIDE + ks * 32 + quad * 8]);
            bf16x8 p1 = *reinterpret_cast<const bf16x8*>(
                &Pb[wave][(16 + l16) * VT_STRIDE + ks * 32 + quad * 8]);
            o0 = __builtin_amdgcn_mfma_f32_16x16x32_bf16(vf, p0, o0, 0, 0, 0);
            o1 = __builtin_amdgcn_mfma_f32_16x16x32_bf16(vf, p1, o1, 0, 0, 0);
        }
#pragma unroll
        for (int t = 0; t < 2; ++t) {
            f32x4 o = t ? o1 : o0;
            ushort_t pk[4];
#pragma unroll
            for (int r = 0; r < 4; ++r) pk[r] = f2bf(o[r]);
            ushort_t* dst = ao + (size_t)(b * LL + q0 + t * 16 + l16) * DD +
                            hh * DH + dt * 16 + quad * 4;
            *(uint2*)dst = *(const uint2*)pk;
        }
    }
}

// ---------------------------------------------------------------------------
// 5) mask + grid aggregation + temporal mean
// ---------------------------------------------------------------------------
__global__ __launch_bounds__(256)
void mask_grid(const float* __restrict__ box, const float* __restrict__ feats,
               float* __restrict__ out)
{
    const int hw = blockIdx.x;
    const int g  = blockIdx.y;
    const int b  = blockIdx.z;
    const int hh = hw / GW, w = hw % GW;
    const float cy = (hh + 0.5f) / (float)GH;
    const float cx = (w  + 0.5f) / (float)GW;
    const int tid = threadIdx.x;

    __shared__ float flg[20];
    if (tid < 20) {
        int t = g * 2 + tid / OO, o = tid % OO;
        const float* bx = box + (size_t)((b * TT + t) * OO + o) * 4;
        float x1 = fminf(bx[0], bx[2]), x2 = fmaxf(bx[0], bx[2]);
        float y1 = fminf(bx[1], bx[3]), y2 = fmaxf(bx[1], bx[3]);
        flg[tid] = (cy >= y1 && cy <= y2 && cx >= x1 && cx <= x2) ? 1.f : 0.f;
    }
    __syncthreads();

    float a0 = 0.f, a1 = 0.f, a2 = 0.f;
#pragma unroll
    for (int p = 0; p < 20; ++p) {
        if (flg[p] != 0.f) {
            int r = (b * TT + g * 2 + p / OO) * OO + (p % OO);
            const float* f = feats + (size_t)r * DD;
            a0 += f[tid]; a1 += f[tid + 256]; a2 += f[tid + 512];
        }
    }
    float* op = out + ((size_t)b * (TGRP * GH * GW) + g * (GH * GW) + hw) * DD;
    op[tid]       = a0 * 0.5f;
    op[tid + 256] = a1 * 0.5f;
    op[tid + 512] = a2 * 0.5f;
}

// ---------------------------------------------------------------------------
extern "C" void kernel_launch(void* const* d_in, const int* in_sizes, int n_in,
                              void* d_out, int out_size, void* d_ws, size_t ws_size,
                              hipStream_t stream)
{
    const float* box  = (const float*)d_in[0];
    const float* cat  = (const float*)d_in[1];
    const float* w1   = (const float*)d_in[2];
    const float* w2   = (const float*)d_in[3];
    const float* ln1g = (const float*)d_in[4];
    const float* ln1b = (const float*)d_in[5];
    const float* wqkv = (const float*)d_in[6];
    const float* wo   = (const float*)d_in[7];
    const float* bo   = (const float*)d_in[8];
    const float* ln2g = (const float*)d_in[9];
    const float* ln2b = (const float*)d_in[10];
    const float* wfc1 = (const float*)d_in[11];
    const float* bfc1 = (const float*)d_in[12];
    const float* wfc2 = (const float*)d_in[13];
    const float* bfc2 = (const float*)d_in[14];
    float* out = (float*)d_out;

    // workspace layout (byte offsets, all 16B aligned)
    char* wsb = (char*)d_ws;
    float*    x     = (float*)   (wsb + 0);           //  7,864,320 B (2560x768 f32)
    ushort_t* qkvb  = (ushort_t*)(wsb + 7864320);     // 11,796,480 B (2560x2304 bf16)
    ushort_t* fc1b  = qkvb;                           // 15,728,640 B overlay (qkv dead)
    ushort_t* hnb   = (ushort_t*)(wsb + 23592960);    //  3,932,160 B
    ushort_t* aob   = (ushort_t*)(wsb + 27525120);    //  3,932,160 B
    ushort_t* wqkvT = (ushort_t*)(wsb + 31457280);    //  3,538,944 B (2304x768)
    ushort_t* woT   = (ushort_t*)(wsb + 34996224);    //  1,179,648 B (768x768)
    ushort_t* wfc1T = (ushort_t*)(wsb + 36175872);    //  4,718,592 B (3072x768)
    ushort_t* wfc2T = (ushort_t*)(wsb + 40894464);    //  4,718,592 B (768x3072)
    // total 45,613,056 B

    transpose_w<<<dim3(2304 / 32, 768 / 32), 256, 0, stream>>>(wqkv, wqkvT, 768, 2304);
    transpose_w<<<dim3(768 / 32, 768 / 32), 256, 0, stream>>>(wo, woT, 768, 768);
    transpose_w<<<dim3(3072 / 32, 768 / 32), 256, 0, stream>>>(wfc1, wfc1T, 768, 3072);
    transpose_w<<<dim3(768 / 32, 3072 / 32), 256, 0, stream>>>(wfc2, wfc2T, 3072, 768);

    box_mlp<<<BL / 8, 256, 0, stream>>>(box, cat, w1, w2, x);
    ln_kernel<<<BL, 256, 0, stream>>>(x, ln1g, ln1b, hnb);
    gemm_mfma<3><<<dim3(18, 20), 256, 0, stream>>>(hnb, DD, wqkvT, DD, nullptr,
                                                   nullptr, qkvb, 3 * DD, DD);
    attention_mfma<<<BATCH * NH, 320, 0, stream>>>(qkvb, aob);
    gemm_mfma<1><<<dim3(6, 20), 256, 0, stream>>>(aob, DD, woT, DD, bo,
                                                  x, nullptr, DD, DD);
    ln_kernel<<<BL, 256, 0, stream>>>(x, ln2g, ln2b, hnb);
    gemm_mfma<2><<<dim3(24, 20), 256, 0, stream>>>(hnb, DD, wfc1T, DD, bfc1,
                                                   nullptr, fc1b, 4 * DD, DD);
    gemm_mfma<1><<<dim3(6, 20), 256, 0, stream>>>(fc1b, 4 * DD, wfc2T, 4 * DD, bfc2,
                                                  x, nullptr, DD, 4 * DD);
    mask_grid<<<dim3(GH * GW, TGRP, BATCH), 256, 0, stream>>>(box, x, out);
}

// Round 5
// 370.158 us; speedup vs baseline: 2.4268x; 1.0955x over previous
//
#include <hip/hip_runtime.h>
#include <hip/hip_bf16.h>
#include <math.h>

// B=16, T=16, O=10, L=160, d=768, heads=12, dh=64, H=W=14, Tr=2.
// Out: (16, 8*196, 768) fp32.

#define BATCH 16
#define TT    16
#define OO    10
#define LL    160
#define BL    2560
#define DD    768
#define NH    12
#define DH    64
#define GH    14
#define GW    14
#define TGRP  8

typedef unsigned short ushort_t;
typedef __attribute__((ext_vector_type(8))) __bf16 bf16x8;
typedef __attribute__((ext_vector_type(4))) float f32x4;

__device__ __forceinline__ ushort_t f2bf(float f) {
    unsigned int u = __float_as_uint(f);
    u += 0x7fffu + ((u >> 16) & 1u);         // RNE
    return (ushort_t)(u >> 16);
}

// ---------------------------------------------------------------------------
// 0) weight convert+transpose: W[K][N] fp32 -> Wt[N][K] bf16
// ---------------------------------------------------------------------------
__global__ __launch_bounds__(256)
void transpose_w(const float* __restrict__ W, ushort_t* __restrict__ Wt, int K, int N)
{
    __shared__ float s[32][33];
    const int n0 = blockIdx.x * 32, k0 = blockIdx.y * 32;
    const int tx = threadIdx.x & 31, ty = threadIdx.x >> 5;   // ty 0..7
#pragma unroll
    for (int r = 0; r < 4; ++r)
        s[ty + r * 8][tx] = W[(size_t)(k0 + ty + r * 8) * N + n0 + tx];
    __syncthreads();
#pragma unroll
    for (int r = 0; r < 4; ++r)
        Wt[(size_t)(n0 + ty + r * 8) * K + k0 + tx] = f2bf(s[tx][ty + r * 8]);
}

// ---------------------------------------------------------------------------
// 1a) box hidden: h = relu(box @ w1) -> bf16 [2560][384]
// ---------------------------------------------------------------------------
__global__ __launch_bounds__(256)
void box_h(const float* __restrict__ box, const float* __restrict__ w1,
           ushort_t* __restrict__ h)
{
    const int idx = blockIdx.x * 256 + threadIdx.x;     // 0..983039
    const int r = idx / 384, j = idx - r * 384;
    const float* bx = box + (size_t)r * 4;
    float v = bx[0] * w1[j] + bx[1] * w1[384 + j] +
              bx[2] * w1[768 + j] + bx[3] * w1[1152 + j];
    h[idx] = f2bf(fmaxf(v, 0.f));
}

// ---------------------------------------------------------------------------
// 2) LayerNorm -> bf16 output
// ---------------------------------------------------------------------------
__global__ __launch_bounds__(256)
void ln_kernel(const float* __restrict__ in, const float* __restrict__ g,
               const float* __restrict__ bvec, ushort_t* __restrict__ out)
{
    const int r = blockIdx.x;
    const int tid = threadIdx.x;
    const float* row = in + (size_t)r * DD;
    float v0 = row[tid], v1 = row[tid + 256], v2 = row[tid + 512];
    float s  = v0 + v1 + v2;
    float s2 = v0 * v0 + v1 * v1 + v2 * v2;
#pragma unroll
    for (int off = 32; off > 0; off >>= 1) {
        s  += __shfl_down(s, off);
        s2 += __shfl_down(s2, off);
    }
    __shared__ float red[8];
    int wave = tid >> 6, lane = tid & 63;
    if (lane == 0) { red[wave] = s; red[wave + 4] = s2; }
    __syncthreads();
    s  = red[0] + red[1] + red[2] + red[3];
    s2 = red[4] + red[5] + red[6] + red[7];
    float mu  = s * (1.f / DD);
    float var = s2 * (1.f / DD) - mu * mu;
    float inv = rsqrtf(var + 1e-5f);
    ushort_t* op = out + (size_t)r * DD;
    op[tid]       = f2bf((v0 - mu) * inv * g[tid]       + bvec[tid]);
    op[tid + 256] = f2bf((v1 - mu) * inv * g[tid + 256] + bvec[tid + 256]);
    op[tid + 512] = f2bf((v2 - mu) * inv * g[tid + 512] + bvec[tid + 512]);
}

// ---------------------------------------------------------------------------
// 3) register-fragment bf16 MFMA GEMM: 1 wave per block, 64x64 tile.
//    No LDS, no barriers: A/B fragments loaded straight from global (bf16x8),
//    2-deep software pipeline (Kper must be a multiple of 64).
//    A[M][K] row-major bf16 (lda), Bt[N][K] row-major bf16 (ldb).
//    MODE 1: Cf += acc + bias (atomicAdd when SPLIT>1; bias only slice 0)
//    MODE 2: Cb = bf16(gelu(acc+bias))
//    MODE 3: Cb = bf16(acc)
//    MODE 4: Cf = relu(acc) + cat[(row%160)][col]
// ---------------------------------------------------------------------------
#define LOADF(aa, bb, kk)                                                        \
    _Pragma("unroll")                                                            \
    for (int i = 0; i < 4; ++i) {                                                \
        aa[i] = *reinterpret_cast<const bf16x8*>(ap + (size_t)(i * 16) * lda + (kk)); \
        bb[i] = *reinterpret_cast<const bf16x8*>(bp + (size_t)(i * 16) * ldb + (kk)); \
    }
#define MFMA16(aa, bb)                                                           \
    _Pragma("unroll")                                                            \
    for (int i = 0; i < 4; ++i)                                                  \
        _Pragma("unroll")                                                        \
        for (int j = 0; j < 4; ++j)                                              \
            acc[i][j] = __builtin_amdgcn_mfma_f32_16x16x32_bf16(aa[i], bb[j], acc[i][j], 0, 0, 0);

template <int MODE, int SPLIT>
__global__ __launch_bounds__(64)
void gemm_rf(const ushort_t* __restrict__ A, int lda,
             const ushort_t* __restrict__ Bt, int ldb,
             const float* __restrict__ bias, const float* __restrict__ cat,
             float* __restrict__ Cf, ushort_t* __restrict__ Cb,
             int ldc, int K)
{
    const int lane = threadIdx.x;
    const int l16 = lane & 15, quad = lane >> 4;
    const int row0 = blockIdx.y * 64, col0 = blockIdx.x * 64;
    const int Kper = K / SPLIT;
    const int k0 = blockIdx.z * Kper;

    const ushort_t* ap = A  + (size_t)(row0 + l16) * lda + k0 + quad * 8;
    const ushort_t* bp = Bt + (size_t)(col0 + l16) * ldb + k0 + quad * 8;

    f32x4 acc[4][4];
#pragma unroll
    for (int i = 0; i < 4; ++i)
#pragma unroll
        for (int j = 0; j < 4; ++j) {
            acc[i][j][0] = 0.f; acc[i][j][1] = 0.f;
            acc[i][j][2] = 0.f; acc[i][j][3] = 0.f;
        }

    bf16x8 a0[4], b0[4], a1[4], b1[4];
    LOADF(a0, b0, 0)
    int kt = 0;
    for (; kt + 64 < Kper; kt += 64) {
        LOADF(a1, b1, kt + 32)
        MFMA16(a0, b0)
        LOADF(a0, b0, kt + 64)
        MFMA16(a1, b1)
    }
    LOADF(a1, b1, kt + 32)
    MFMA16(a0, b0)
    MFMA16(a1, b1)

    // epilogue: C/D layout col=lane&15, row=(lane>>4)*4+reg
    const int q4 = quad * 4;
#pragma unroll
    for (int i = 0; i < 4; ++i)
#pragma unroll
        for (int j = 0; j < 4; ++j) {
            const int gcol = col0 + j * 16 + l16;
            const float bj = (MODE == 1 || MODE == 2)
                               ? ((SPLIT == 1 || blockIdx.z == 0) ? bias[gcol] : 0.f)
                               : 0.f;
#pragma unroll
            for (int r = 0; r < 4; ++r) {
                const int grow = row0 + i * 16 + q4 + r;
                const size_t idx = (size_t)grow * ldc + gcol;
                const float v = acc[i][j][r];
                if (MODE == 1) {
                    if (SPLIT > 1) atomicAdd(&Cf[idx], v + bj);
                    else           Cf[idx] += v + bj;
                } else if (MODE == 2) {
                    const float u = v + bj;
                    Cb[idx] = f2bf(0.5f * u * (1.f + erff(u * 0.70710678118654752f)));
                } else if (MODE == 3) {
                    Cb[idx] = f2bf(v);
                } else {
                    Cf[idx] = fmaxf(v, 0.f) + cat[(size_t)(grow % LL) * DD + gcol];
                }
            }
        }
}

// ---------------------------------------------------------------------------
// 4) MFMA attention: block per (b,head), 5 waves; output written back into
//    the (dead) q-slot of qkv. Frag layouts HW-verified by gemm path.
// ---------------------------------------------------------------------------
#define KS_STRIDE 72
#define VT_STRIDE 168
__global__ __launch_bounds__(320)
void attention_mfma(ushort_t* __restrict__ qkv)
{
    __shared__ ushort_t Ks[160 * KS_STRIDE];
    __shared__ ushort_t Vt[64 * VT_STRIDE];
    __shared__ ushort_t Pb[5][32 * VT_STRIDE];

    const int b  = blockIdx.x / NH;
    const int hh = blockIdx.x % NH;
    ushort_t* basew = qkv + (size_t)b * LL * (3 * DD) + hh * DH;
    const ushort_t* base = basew;
    const int tid  = threadIdx.x;
    const int wave = tid >> 6, lane = tid & 63;
    const int l16 = lane & 15, quad = lane >> 4;

    // ---- stage K rows and V transposed ----
#pragma unroll
    for (int it = 0; it < 4; ++it) {
        int idx = tid + it * 320;                 // 0..1279
        int l = idx >> 3, c8 = (idx & 7) * 8;
        uint4 kv = *(const uint4*)(base + (size_t)l * (3 * DD) + DD + c8);
        *(uint4*)&Ks[l * KS_STRIDE + c8] = kv;
        uint4 vv = *(const uint4*)(base + (size_t)l * (3 * DD) + 2 * DD + c8);
        ushort_t e[8];
        *(uint4*)e = vv;
#pragma unroll
        for (int i = 0; i < 8; ++i)
            Vt[(c8 + i) * VT_STRIDE + l] = e[i];
    }

    // ---- Q fragments straight from global ----
    const int q0 = wave * 32;
    bf16x8 qf[2][2];
#pragma unroll
    for (int t = 0; t < 2; ++t)
#pragma unroll
        for (int k = 0; k < 2; ++k)
            qf[t][k] = *reinterpret_cast<const bf16x8*>(
                base + (size_t)(q0 + t * 16 + l16) * (3 * DD) + k * 32 + quad * 8);

    __syncthreads();

    // ---- S = QK^T ----
    f32x4 S0[10], S1[10];
#pragma unroll
    for (int nt = 0; nt < 10; ++nt) {
        f32x4 z = {0.f, 0.f, 0.f, 0.f};
        const ushort_t* kb = &Ks[(nt * 16 + l16) * KS_STRIDE + quad * 8];
        bf16x8 kf0 = *reinterpret_cast<const bf16x8*>(kb);
        bf16x8 kf1 = *reinterpret_cast<const bf16x8*>(kb + 32);
        f32x4 a0 = __builtin_amdgcn_mfma_f32_16x16x32_bf16(qf[0][0], kf0, z, 0, 0, 0);
        S0[nt]   = __builtin_amdgcn_mfma_f32_16x16x32_bf16(qf[0][1], kf1, a0, 0, 0, 0);
        f32x4 a1 = __builtin_amdgcn_mfma_f32_16x16x32_bf16(qf[1][0], kf0, z, 0, 0, 0);
        S1[nt]   = __builtin_amdgcn_mfma_f32_16x16x32_bf16(qf[1][1], kf1, a1, 0, 0, 0);
    }

    // ---- softmax per tile; P (already / l) to wave-private LDS ----
#pragma unroll
    for (int t = 0; t < 2; ++t) {
        f32x4* S = t ? S1 : S0;
        float mrow[4] = {-1e30f, -1e30f, -1e30f, -1e30f};
#pragma unroll
        for (int nt = 0; nt < 10; ++nt)
#pragma unroll
            for (int r = 0; r < 4; ++r) {
                S[nt][r] *= 0.125f;
                mrow[r] = fmaxf(mrow[r], S[nt][r]);
            }
#pragma unroll
        for (int r = 0; r < 4; ++r) {
            mrow[r] = fmaxf(mrow[r], __shfl_xor(mrow[r], 1));
            mrow[r] = fmaxf(mrow[r], __shfl_xor(mrow[r], 2));
            mrow[r] = fmaxf(mrow[r], __shfl_xor(mrow[r], 4));
            mrow[r] = fmaxf(mrow[r], __shfl_xor(mrow[r], 8));
        }
        float lsum[4] = {0.f, 0.f, 0.f, 0.f};
#pragma unroll
        for (int nt = 0; nt < 10; ++nt)
#pragma unroll
            for (int r = 0; r < 4; ++r) {
                float e = __expf(S[nt][r] - mrow[r]);
                S[nt][r] = e;
                lsum[r] += e;
            }
#pragma unroll
        for (int r = 0; r < 4; ++r) {
            lsum[r] += __shfl_xor(lsum[r], 1);
            lsum[r] += __shfl_xor(lsum[r], 2);
            lsum[r] += __shfl_xor(lsum[r], 4);
            lsum[r] += __shfl_xor(lsum[r], 8);
            lsum[r] = 1.f / lsum[r];
        }
#pragma unroll
        for (int nt = 0; nt < 10; ++nt)
#pragma unroll
            for (int r = 0; r < 4; ++r)
                Pb[wave][(t * 16 + quad * 4 + r) * VT_STRIDE + nt * 16 + l16] =
                    f2bf(S[nt][r] * lsum[r]);
    }
    asm volatile("s_waitcnt lgkmcnt(0)" ::: "memory");   // wave-local P write->read

    // ---- O^T = Vt . P^T ; write into q-slot ----
#pragma unroll
    for (int dt = 0; dt < 4; ++dt) {
        f32x4 o0 = {0.f, 0.f, 0.f, 0.f}, o1 = {0.f, 0.f, 0.f, 0.f};
#pragma unroll
        for (int ks = 0; ks < 5; ++ks) {
            bf16x8 vf = *reinterpret_cast<const bf16x8*>(
                &Vt[(dt * 16 + l16) * VT_STRIDE + ks * 32 + quad * 8]);
            bf16x8 p0 = *reinterpret_cast<const bf16x8*>(
                &Pb[wave][(l16) * VT_STRIDE + ks * 32 + quad * 8]);
            bf16x8 p1 = *reinterpret_cast<const bf16x8*>(
                &Pb[wave][(16 + l16) * VT_STRIDE + ks * 32 + quad * 8]);
            o0 = __builtin_amdgcn_mfma_f32_16x16x32_bf16(vf, p0, o0, 0, 0, 0);
            o1 = __builtin_amdgcn_mfma_f32_16x16x32_bf16(vf, p1, o1, 0, 0, 0);
        }
#pragma unroll
        for (int t = 0; t < 2; ++t) {
            f32x4 o = t ? o1 : o0;
            ushort_t pk[4];
#pragma unroll
            for (int r = 0; r < 4; ++r) pk[r] = f2bf(o[r]);
            ushort_t* dst = basew + (size_t)(q0 + t * 16 + l16) * (3 * DD) +
                            dt * 16 + quad * 4;
            *(uint2*)dst = *(const uint2*)pk;
        }
    }
}

// ---------------------------------------------------------------------------
// 5) mask + grid aggregation + temporal mean
// ---------------------------------------------------------------------------
__global__ __launch_bounds__(256)
void mask_grid(const float* __restrict__ box, const float* __restrict__ feats,
               float* __restrict__ out)
{
    const int hw = blockIdx.x;
    const int g  = blockIdx.y;
    const int b  = blockIdx.z;
    const int hh = hw / GW, w = hw % GW;
    const float cy = (hh + 0.5f) / (float)GH;
    const float cx = (w  + 0.5f) / (float)GW;
    const int tid = threadIdx.x;

    __shared__ float flg[20];
    if (tid < 20) {
        int t = g * 2 + tid / OO, o = tid % OO;
        const float* bx = box + (size_t)((b * TT + t) * OO + o) * 4;
        float x1 = fminf(bx[0], bx[2]), x2 = fmaxf(bx[0], bx[2]);
        float y1 = fminf(bx[1], bx[3]), y2 = fmaxf(bx[1], bx[3]);
        flg[tid] = (cy >= y1 && cy <= y2 && cx >= x1 && cx <= x2) ? 1.f : 0.f;
    }
    __syncthreads();

    float a0 = 0.f, a1 = 0.f, a2 = 0.f;
#pragma unroll
    for (int p = 0; p < 20; ++p) {
        if (flg[p] != 0.f) {
            int r = (b * TT + g * 2 + p / OO) * OO + (p % OO);
            const float* f = feats + (size_t)r * DD;
            a0 += f[tid]; a1 += f[tid + 256]; a2 += f[tid + 512];
        }
    }
    float* op = out + ((size_t)b * (TGRP * GH * GW) + g * (GH * GW) + hw) * DD;
    op[tid]       = a0 * 0.5f;
    op[tid + 256] = a1 * 0.5f;
    op[tid + 512] = a2 * 0.5f;
}

// ---------------------------------------------------------------------------
extern "C" void kernel_launch(void* const* d_in, const int* in_sizes, int n_in,
                              void* d_out, int out_size, void* d_ws, size_t ws_size,
                              hipStream_t stream)
{
    const float* box  = (const float*)d_in[0];
    const float* cat  = (const float*)d_in[1];
    const float* w1   = (const float*)d_in[2];
    const float* w2   = (const float*)d_in[3];
    const float* ln1g = (const float*)d_in[4];
    const float* ln1b = (const float*)d_in[5];
    const float* wqkv = (const float*)d_in[6];
    const float* wo   = (const float*)d_in[7];
    const float* bo   = (const float*)d_in[8];
    const float* ln2g = (const float*)d_in[9];
    const float* ln2b = (const float*)d_in[10];
    const float* wfc1 = (const float*)d_in[11];
    const float* bfc1 = (const float*)d_in[12];
    const float* wfc2 = (const float*)d_in[13];
    const float* bfc2 = (const float*)d_in[14];
    float* out = (float*)d_out;

    // workspace layout (byte offsets, 16B aligned), total 44,236,800 B
    char* wsb = (char*)d_ws;
    float*    x     = (float*)   (wsb + 0);           //  7,864,320 (2560x768 f32)
    ushort_t* qkvb  = (ushort_t*)(wsb + 7864320);     // 15,728,640 (qkv 2560x2304 / fc1 2560x3072 overlay)
    ushort_t* fc1b  = qkvb;
    ushort_t* hnb   = (ushort_t*)(wsb + 23592960);    //  3,932,160 (2560x768)
    ushort_t* wqkvT = (ushort_t*)(wsb + 27525120);    //  3,538,944 (2304x768)
    ushort_t* woT   = (ushort_t*)(wsb + 31064064);    //  1,179,648 (768x768)
    ushort_t* wfc1T = (ushort_t*)(wsb + 32243712);    //  4,718,592 (3072x768)
    ushort_t* wfc2T = (ushort_t*)(wsb + 36962304);    //  4,718,592 (768x3072)
    ushort_t* w2T   = (ushort_t*)(wsb + 41680896);    //    589,824 (768x384)
    ushort_t* h     = (ushort_t*)(wsb + 42270720);    //  1,966,080 (2560x384)

    transpose_w<<<dim3(2304 / 32, 768 / 32), 256, 0, stream>>>(wqkv, wqkvT, 768, 2304);
    transpose_w<<<dim3(768 / 32, 768 / 32), 256, 0, stream>>>(wo, woT, 768, 768);
    transpose_w<<<dim3(3072 / 32, 768 / 32), 256, 0, stream>>>(wfc1, wfc1T, 768, 3072);
    transpose_w<<<dim3(768 / 32, 3072 / 32), 256, 0, stream>>>(wfc2, wfc2T, 3072, 768);
    transpose_w<<<dim3(768 / 32, 384 / 32), 256, 0, stream>>>(w2, w2T, 384, 768);

    box_h<<<BL * 384 / 256, 256, 0, stream>>>(box, w1, h);
    // x = relu(h @ w2) + cat[t,o]
    gemm_rf<4, 1><<<dim3(12, 40, 1), 64, 0, stream>>>(h, 384, w2T, 384, nullptr, cat,
                                                      x, nullptr, DD, 384);
    ln_kernel<<<BL, 256, 0, stream>>>(x, ln1g, ln1b, hnb);
    gemm_rf<3, 1><<<dim3(36, 40, 1), 64, 0, stream>>>(hnb, DD, wqkvT, DD, nullptr, nullptr,
                                                      nullptr, qkvb, 3 * DD, DD);
    attention_mfma<<<BATCH * NH, 320, 0, stream>>>(qkvb);
    // x += attn_out @ wo + bo   (A = q-slot of qkv, lda = 2304; split-K=2)
    gemm_rf<1, 2><<<dim3(12, 40, 2), 64, 0, stream>>>(qkvb, 3 * DD, woT, DD, bo, nullptr,
                                                      x, nullptr, DD, DD);
    ln_kernel<<<BL, 256, 0, stream>>>(x, ln2g, ln2b, hnb);
    gemm_rf<2, 1><<<dim3(48, 40, 1), 64, 0, stream>>>(hnb, DD, wfc1T, DD, bfc1, nullptr,
                                                      nullptr, fc1b, 4 * DD, DD);
    // x += gelu_fc1 @ wfc2 + bfc2  (split-K=4)
    gemm_rf<1, 4><<<dim3(12, 40, 4), 64, 0, stream>>>(fc1b, 4 * DD, wfc2T, 4 * DD, bfc2, nullptr,
                                                      x, nullptr, DD, 4 * DD);
    mask_grid<<<dim3(GH * GW, TGRP, BATCH), 256, 0, stream>>>(box, x, out);
}